// Round 12
// baseline (108.951 us; speedup 1.0000x reference)
//
#include <hip/hip_runtime.h>

// Problem constants
#define K_CODES 512
#define DIM 80
#define SEQ 4096
#define NVEC 131072
#define NELEM ((size_t)NVEC * DIM)
#define VPB 64                       // vectors per block: 4 waves x 1 set x 16
#define NTILES 16                    // 32-code tiles
#define TILE_BYTES 12288             // 768 short8 per tile (2 fragment-groups)

typedef short short8 __attribute__((ext_vector_type(8)));
typedef float f32x4 __attribute__((ext_vector_type(4)));

// ws layout: ghist[512] @0 | gsq @2048 | wsq[512] @4096 | wfrag @8192 (196608 B) | bk @204800
#define WS_GSQ   2048
#define WS_WSQ   4096
#define WS_WFRAG 8192
#define WS_BK    (8192 + 196608)

__device__ __forceinline__ unsigned short f2bf(float f) {
    union { float f; unsigned int u; } c; c.f = f;
    unsigned int r = c.u + 0x7FFFu + ((c.u >> 16) & 1u);   // RNE
    return (unsigned short)(r >> 16);
}
__device__ __forceinline__ float bf2f(unsigned short h) {
    union { float f; unsigned int u; } c; c.u = ((unsigned int)h) << 16;
    return c.f;
}

__device__ __forceinline__ void gload_lds16(const void* g, void* l) {
    __builtin_amdgcn_global_load_lds(
        (const __attribute__((address_space(1))) void*)g,
        (__attribute__((address_space(3))) void*)l, 16, 0, 0);
}

// Fused setup: wfrag (fragment-ordered split codebook) + wsq (row norms).
// wfrag: [t16 0..31][g 0..5][lane 0..63] short8; g<3: hi,ks=g; g>=3: lo,ks=g-3;
//        lane=(cg<<4)|cl; value = w{hi,lo}[code=t16*16+cl][c=ks*32+cg*8 ..+8)
// A 32-code tile t is the pair of 16-code tiles {2t, 2t+1} = bytes [t*12288,+12288).
__global__ void vq_setup(const float* __restrict__ weight,
                         short8* __restrict__ wf, float* __restrict__ wsq)
{
    int idx = blockIdx.x * 256 + threadIdx.x;   // 48 blocks -> 12288
    if (blockIdx.x < 2) {
        int k = blockIdx.x * 256 + threadIdx.x;
        const float* w = weight + (size_t)k * DIM;
        float s = 0.f;
#pragma unroll
        for (int c = 0; c < DIM; ++c) s = fmaf(w[c], w[c], s);
        wsq[k] = s;
    }
    int t   = idx / 384;
    int rem = idx - t * 384;
    int g   = rem >> 6, l = rem & 63;
    int cl  = l & 15, cg = l >> 4;
    int ks  = g % 3, h = g / 3;
    int code = t * 16 + cl;
    int c0 = ks * 32 + cg * 8;
    short8 v;
#pragma unroll
    for (int j = 0; j < 8; ++j) {
        int c = c0 + j;
        unsigned short r = 0;
        if (c < DIM) {
            float f = weight[(size_t)code * DIM + c];
            unsigned short hb = f2bf(f);
            r = h ? f2bf(f - bf2f(hb)) : hb;
        }
        v[j] = (short)r;
    }
    wf[idx] = v;
}

// Distance GEMM + argmin. 1 A-set/wave (16 vec), 32-code tiles -> 16 phases.
// Per phase: issue stage(t+1) [3x gload_lds16/wave], s_waitcnt vmcnt(3)
// (stage(t) landed, t+1 stays in flight), 12 ds_read_b128 + 18 MFMA + fold,
// raw s_barrier. In-loop VMEM is staging ONLY (wsq in LDS, A in registers).
__global__ __launch_bounds__(256, 3) void vq_argmin(
    const float* __restrict__ x, const short8* __restrict__ wf,
    const float* __restrict__ wsq,
    int* __restrict__ bk, int* __restrict__ ghist)
{
    __shared__ short8 bbuf[2][768];   // 2 x 12 KB, fragment-ordered 32-code tiles
    __shared__ float wsq_lds[K_CODES];
    __shared__ int lhist[K_CODES];

    const int tid = threadIdx.x;
    for (int i = tid; i < K_CODES; i += 256) { lhist[i] = 0; wsq_lds[i] = wsq[i]; }

    const int v0 = blockIdx.x * VPB;
    const int b  = v0 >> 12;
    const int l0 = v0 & 4095;
    const float* xbase = x + (size_t)b * DIM * SEQ + l0;

    const int lane = tid & 63, wid = tid >> 6;
    const int cg = lane >> 4;          // k-group 0..3
    const int cl = lane & 15;          // A row / B col
    const int ar = wid * 16 + cl;      // local vector index (A row)

    // ---- stage tile 0: each wave 3 KB (wave-uniform base + lane*16) ----
    {
        const char* src = (const char*)wf + wid * 3072 + lane * 16;
        char* dst = (char*)&bbuf[0][0] + wid * 3072 + lane * 16;
        gload_lds16(src, dst);
        gload_lds16(src + 1024, dst + 1024);
        gload_lds16(src + 2048, dst + 2048);
    }

    // ---- A fragments (1 set, hi/lo), direct from global ----
    short8 ahi[3], alo[3];
#pragma unroll
    for (int ks = 0; ks < 3; ++ks) {
#pragma unroll
        for (int j = 0; j < 8; ++j) {
            int c = ks * 32 + cg * 8 + j;
            unsigned short hb = 0, lb = 0;
            if (c < DIM) {
                float f = xbase[(size_t)c * SEQ + ar];
                hb = f2bf(f);
                lb = f2bf(f - bf2f(hb));
            }
            ahi[ks][j] = (short)hb;
            alo[ks][j] = (short)lb;
        }
    }

    float bestd[2][4];
    int   bestk[2][4];
#pragma unroll
    for (int g = 0; g < 2; ++g)
#pragma unroll
        for (int r = 0; r < 4; ++r) { bestd[g][r] = 3.4028235e38f; bestk[g][r] = 0; }

    __syncthreads();   // drains A loads + stage(0); LDS init visible

    for (int t = 0; t < NTILES; ++t) {
        // issue next tile's staging into buf[(t+1)&1] (its readers, phase t-1,
        // all finished at the barrier that ended phase t-1)
        if (t + 1 < NTILES) {
            const char* src = (const char*)wf + (size_t)(t + 1) * TILE_BYTES + wid * 3072 + lane * 16;
            char* dst = (char*)&bbuf[(t + 1) & 1][0] + wid * 3072 + lane * 16;
            gload_lds16(src, dst);
            gload_lds16(src + 1024, dst + 1024);
            gload_lds16(src + 2048, dst + 2048);
            asm volatile("s_waitcnt vmcnt(3)" ::: "memory");   // stage(t) landed
        } else {
            asm volatile("s_waitcnt vmcnt(0)" ::: "memory");
        }
        __builtin_amdgcn_sched_barrier(0);

        const short8* bb = &bbuf[t & 1][0];
        short8 g0h0 = bb[lane],       g0h1 = bb[64 + lane],  g0h2 = bb[128 + lane];
        short8 g0l0 = bb[192 + lane], g0l1 = bb[256 + lane], g0l2 = bb[320 + lane];
        short8 g1h0 = bb[384 + lane], g1h1 = bb[448 + lane], g1h2 = bb[512 + lane];
        short8 g1l0 = bb[576 + lane], g1l1 = bb[640 + lane], g1l2 = bb[704 + lane];

        f32x4 a00 = {0.f,0.f,0.f,0.f}, a01 = {0.f,0.f,0.f,0.f}, a02 = {0.f,0.f,0.f,0.f};
        f32x4 a10 = {0.f,0.f,0.f,0.f}, a11 = {0.f,0.f,0.f,0.f}, a12 = {0.f,0.f,0.f,0.f};
        __builtin_amdgcn_s_setprio(1);
        // R9-identical per-group sequence: aX[ks] = hh(ks)+hl(ks)+lh(ks), 3-deep chains
        a00 = __builtin_amdgcn_mfma_f32_16x16x32_bf16(ahi[0], g0h0, a00, 0, 0, 0);
        a01 = __builtin_amdgcn_mfma_f32_16x16x32_bf16(ahi[1], g0h1, a01, 0, 0, 0);
        a02 = __builtin_amdgcn_mfma_f32_16x16x32_bf16(ahi[2], g0h2, a02, 0, 0, 0);
        a10 = __builtin_amdgcn_mfma_f32_16x16x32_bf16(ahi[0], g1h0, a10, 0, 0, 0);
        a11 = __builtin_amdgcn_mfma_f32_16x16x32_bf16(ahi[1], g1h1, a11, 0, 0, 0);
        a12 = __builtin_amdgcn_mfma_f32_16x16x32_bf16(ahi[2], g1h2, a12, 0, 0, 0);
        a00 = __builtin_amdgcn_mfma_f32_16x16x32_bf16(ahi[0], g0l0, a00, 0, 0, 0);
        a01 = __builtin_amdgcn_mfma_f32_16x16x32_bf16(ahi[1], g0l1, a01, 0, 0, 0);
        a02 = __builtin_amdgcn_mfma_f32_16x16x32_bf16(ahi[2], g0l2, a02, 0, 0, 0);
        a10 = __builtin_amdgcn_mfma_f32_16x16x32_bf16(ahi[0], g1l0, a10, 0, 0, 0);
        a11 = __builtin_amdgcn_mfma_f32_16x16x32_bf16(ahi[1], g1l1, a11, 0, 0, 0);
        a12 = __builtin_amdgcn_mfma_f32_16x16x32_bf16(ahi[2], g1l2, a12, 0, 0, 0);
        a00 = __builtin_amdgcn_mfma_f32_16x16x32_bf16(alo[0], g0h0, a00, 0, 0, 0);
        a01 = __builtin_amdgcn_mfma_f32_16x16x32_bf16(alo[1], g0h1, a01, 0, 0, 0);
        a02 = __builtin_amdgcn_mfma_f32_16x16x32_bf16(alo[2], g0h2, a02, 0, 0, 0);
        a10 = __builtin_amdgcn_mfma_f32_16x16x32_bf16(alo[0], g1h0, a10, 0, 0, 0);
        a11 = __builtin_amdgcn_mfma_f32_16x16x32_bf16(alo[1], g1h1, a11, 0, 0, 0);
        a12 = __builtin_amdgcn_mfma_f32_16x16x32_bf16(alo[2], g1h2, a12, 0, 0, 0);
        __builtin_amdgcn_s_setprio(0);

        const int c0 = t * 32 + cl;
        float w0 = wsq_lds[c0];
        float w1 = wsq_lds[c0 + 16];
#pragma unroll
        for (int r = 0; r < 4; ++r) {
            float d0 = a00[r] + a01[r] + a02[r];
            float q0 = fmaf(-2.f, d0, w0);
            if (q0 < bestd[0][r]) { bestd[0][r] = q0; bestk[0][r] = c0; }
            float d1 = a10[r] + a11[r] + a12[r];
            float q1 = fmaf(-2.f, d1, w1);
            if (q1 < bestd[1][r]) { bestd[1][r] = q1; bestk[1][r] = c0 + 16; }
        }

        __builtin_amdgcn_s_barrier();   // all reads of bbuf[t&1] done block-wide
    }

    // ---- merge the two column groups (lexicographic), then cross-lane argmin ----
#pragma unroll
    for (int r = 0; r < 4; ++r) {
        float d = bestd[0][r]; int k = bestk[0][r];
        if (bestd[1][r] < d || (bestd[1][r] == d && bestk[1][r] < k)) {
            d = bestd[1][r]; k = bestk[1][r];
        }
#pragma unroll
        for (int off = 1; off < 16; off <<= 1) {
            float od = __shfl_xor(d, off, 64);
            int   ok = __shfl_xor(k, off, 64);
            if (od < d || (od == d && ok < k)) { d = od; k = ok; }
        }
        if (cl == 0) {
            int vloc = wid * 16 + cg * 4 + r;    // D row = (lane>>4)*4 + reg
            bk[v0 + vloc] = k;
            atomicAdd(&lhist[k], 1);
        }
    }
    __syncthreads();
    for (int i = tid; i < K_CODES; i += 256) {
        int cnt = lhist[i];
        if (cnt) atomicAdd(&ghist[i], cnt);
    }
}

// Memory-bound epilogue: thread = vector. Row-gather codebook (float4,
// exact fp32), coalesced x reads / out writes, loss accumulation.
__global__ __launch_bounds__(256) void vq_epilogue(
    const float* __restrict__ x, const float* __restrict__ weight,
    const int* __restrict__ bk, float* __restrict__ out,
    float* __restrict__ gsq)
{
    __shared__ float lsum[4];
    const int tid = threadIdx.x;
    const int v = blockIdx.x * 256 + tid;
    const int b = v >> 12;
    const int l = v & 4095;
    const float* xp = x + (size_t)b * DIM * SEQ + l;
    const float* wr = weight + (size_t)bk[v] * DIM;
    float* op = out + 1 + (size_t)b * DIM * SEQ + l;

    float sq = 0.f;
#pragma unroll
    for (int c = 0; c < DIM; c += 4) {
        float4 wv = *(const float4*)(wr + c);
        float x0 = xp[(size_t)(c + 0) * SEQ];
        float x1 = xp[(size_t)(c + 1) * SEQ];
        float x2 = xp[(size_t)(c + 2) * SEQ];
        float x3 = xp[(size_t)(c + 3) * SEQ];
        float e0 = wv.x - x0, e1 = wv.y - x1, e2 = wv.z - x2, e3 = wv.w - x3;
        sq = fmaf(e0, e0, sq);
        sq = fmaf(e1, e1, sq);
        sq = fmaf(e2, e2, sq);
        sq = fmaf(e3, e3, sq);
        op[(size_t)(c + 0) * SEQ] = wv.x;
        op[(size_t)(c + 1) * SEQ] = wv.y;
        op[(size_t)(c + 2) * SEQ] = wv.z;
        op[(size_t)(c + 3) * SEQ] = wv.w;
    }

#pragma unroll
    for (int off = 32; off; off >>= 1) sq += __shfl_down(sq, off, 64);
    if ((tid & 63) == 0) lsum[tid >> 6] = sq;
    __syncthreads();
    if (tid == 0) {
        float s = lsum[0] + lsum[1] + lsum[2] + lsum[3];
        atomicAdd(gsq, s);
    }
}

__global__ void vq_finalize(const int* __restrict__ hist,
                            const float* __restrict__ gsq,
                            float* __restrict__ out, int out_last)
{
    __shared__ float part[8];
    int t = threadIdx.x;  // 512 threads
    float p = (float)hist[t] * (1.0f / (float)NVEC);
    float term = p * logf(p + 1e-10f);
#pragma unroll
    for (int off = 32; off; off >>= 1) term += __shfl_down(term, off, 64);
    if ((t & 63) == 0) part[t >> 6] = term;
    __syncthreads();
    if (t == 0) {
        float s = 0.f;
#pragma unroll
        for (int i = 0; i < 8; ++i) s += part[i];
        out[out_last] = expf(-s);
        out[0] = 1.25f * gsq[0] / (float)NELEM;
    }
}

extern "C" void kernel_launch(void* const* d_in, const int* in_sizes, int n_in,
                              void* d_out, int out_size, void* d_ws, size_t ws_size,
                              hipStream_t stream) {
    const float* x = (const float*)d_in[0];
    const float* weight = (const float*)d_in[1];
    float* out = (float*)d_out;

    int* ghist = (int*)d_ws;
    float* gsq = (float*)((char*)d_ws + WS_GSQ);
    float* wsq = (float*)((char*)d_ws + WS_WSQ);
    short8* wf = (short8*)((char*)d_ws + WS_WFRAG);
    int* bk = (int*)((char*)d_ws + WS_BK);

    hipMemsetAsync(d_ws, 0, 2052, stream);

    vq_setup<<<48, 256, 0, stream>>>(weight, wf, wsq);
    vq_argmin<<<NVEC / VPB, 256, 0, stream>>>(x, wf, wsq, bk, ghist);
    vq_epilogue<<<NVEC / 256, 256, 0, stream>>>(x, weight, bk, out, gsq);
    vq_finalize<<<1, K_CODES, 0, stream>>>(ghist, gsq, out, out_size - 1);
}